// Round 5
// baseline (347.174 us; speedup 1.0000x reference)
//
#include <hip/hip_runtime.h>
#include <math.h>

// GlobalAttention, single-streaming-pass version (v5).
//   logits[b,h,n] = qW[h,:].LN(x[b,n,:])  (q folded through Wkv_k, LN folded via mu/rstd)
//   s[b,h,:]      = sum_n softmax(logits) * rstd_n * x[b,n,:]  (chunk partials, merged)
//   out           = cf + (Wkv_v @ (gamma*(S-UN)/E + beta)) @ proj_W.T + proj_b
// v5: no online max (logit std ~0.35 analytically; p = exp(min(l,75)) exact, m=0),
// stats computed once per row (wave wid owns row wid), 2 barriers/tile,
// branchless straight-line phase B, global_load_lds staging (no VGPR round-trip).

#define BB 16
#define NN 4096
#define CC 1024
#define HH 8
#define DD 128
#define CHUNKS 64   // chunks per batch
#define RPB 64      // rows per block
#define TPT 4       // rows per tile
#define NT 16       // tiles per block

constexpr float EPS_ = 1e-5f;
constexpr float SCALE_ = 0.03125f; // 1024^-0.5

__device__ __forceinline__ float wsum(float v) {
#pragma unroll
  for (int o = 32; o; o >>= 1) v += __shfl_xor(v, o, 64);
  return v;
}

// DPP wave reduction: sum of all 64 lanes lands in lane 63 (VALU pipe, no LDS).
__device__ __forceinline__ float dpp_sum63(float v) {
  int t;
  t = __builtin_amdgcn_update_dpp(0, __float_as_int(v), 0x111, 0xf, 0xf, true);  v += __int_as_float(t);
  t = __builtin_amdgcn_update_dpp(0, __float_as_int(v), 0x112, 0xf, 0xf, true);  v += __int_as_float(t);
  t = __builtin_amdgcn_update_dpp(0, __float_as_int(v), 0x114, 0xf, 0xf, true);  v += __int_as_float(t);
  t = __builtin_amdgcn_update_dpp(0, __float_as_int(v), 0x118, 0xf, 0xf, true);  v += __int_as_float(t);
  t = __builtin_amdgcn_update_dpp(0, __float_as_int(v), 0x142, 0xa, 0xf, false); v += __int_as_float(t);
  t = __builtin_amdgcn_update_dpp(0, __float_as_int(v), 0x143, 0xc, 0xf, false); v += __int_as_float(t);
  return v;
}

// reduce + broadcast: total of 64 lanes as a wave-uniform value
__device__ __forceinline__ float rsum_u(float v) {
  return __int_as_float(__builtin_amdgcn_readlane(__float_as_int(dpp_sum63(v)), 63));
}

__device__ __forceinline__ float dot4(const float4& a, const float4& b) {
  return a.x * b.x + a.y * b.y + a.z * b.z + a.w * b.w;
}
__device__ __forceinline__ void fma4(float4& a, float s, const float4& v) {
  a.x += s * v.x; a.y += s * v.y; a.z += s * v.z; a.w += s * v.w;
}

// barrier that waits LDS ops only (keeps global_load_lds prefetch in flight)
__device__ __forceinline__ void bar_lgkm() {
  asm volatile("s_waitcnt lgkmcnt(0)" ::: "memory");
  __builtin_amdgcn_sched_barrier(0);
  __builtin_amdgcn_s_barrier();
  __builtin_amdgcn_sched_barrier(0);
}
// barrier that waits all outstanding global_load_lds (tile ready)
__device__ __forceinline__ void bar_vm() {
  asm volatile("s_waitcnt vmcnt(0)" ::: "memory");
  __builtin_amdgcn_sched_barrier(0);
  __builtin_amdgcn_s_barrier();
  __builtin_amdgcn_sched_barrier(0);
}

// stage one 4-row tile (16 KB) into LDS: 4 x global_load_lds dwordx4 per thread.
__device__ __forceinline__ void stage_tile(const float* gsrc, float* lbase,
                                           int wid, int lane) {
#pragma unroll
  for (int k = 0; k < 4; ++k) {
    const char* g = (const char*)gsrc + k * 4096 + wid * 1024 + lane * 16;
    char* l = (char*)lbase + k * 4096 + wid * 1024;
    __builtin_amdgcn_global_load_lds(
        (const __attribute__((address_space(1))) void*)g,
        (__attribute__((address_space(3))) void*)l, 16, 0, 0);
  }
}

// ---- k0b: LN(class_feature) in-block, then qvec[j] = ln_cf . Wq[j,:] ----
__global__ __launch_bounds__(256) void k0b(const float* __restrict__ cf,
                                           const float* __restrict__ g,
                                           const float* __restrict__ be,
                                           const float* __restrict__ Wq,
                                           float* __restrict__ qvec) {
  __shared__ __align__(16) float lnbuf[CC];
  __shared__ float red[8];
  int t = threadIdx.x, lane = t & 63, wid = t >> 6;
  float x[4];
  float s = 0.f, s2 = 0.f;
#pragma unroll
  for (int j = 0; j < 4; ++j) {
    x[j] = cf[t * 4 + j];
    s += x[j];
    s2 += x[j] * x[j];
  }
  s = wsum(s);
  s2 = wsum(s2);
  if (lane == 0) { red[wid] = s; red[4 + wid] = s2; }
  __syncthreads();
  float S = red[0] + red[1] + red[2] + red[3];
  float S2 = red[4] + red[5] + red[6] + red[7];
  float mu = S * (1.f / CC);
  float rstd = rsqrtf(S2 * (1.f / CC) - mu * mu + EPS_);
#pragma unroll
  for (int j = 0; j < 4; ++j)
    lnbuf[t * 4 + j] = (x[j] - mu) * rstd * g[t * 4 + j] + be[t * 4 + j];
  __syncthreads();
  int j = blockIdx.x * 4 + wid;
  const float4* wr = (const float4*)(Wq + (size_t)j * CC);
  const float4* l4 = (const float4*)lnbuf;
  float a = 0.f;
#pragma unroll
  for (int k = 0; k < 4; ++k) a += dot4(wr[lane + 64 * k], l4[lane + 64 * k]);
  a = wsum(a);
  if (lane == 0) qvec[j] = a;
}

// ---- k0c: qW[h,c] = scale*sum_d qvec[h*D+d]*Wkv[h*D+d,c]; qWg = qW*gamma ----
__global__ __launch_bounds__(256) void k0c(const float* __restrict__ qvec,
                                           const float* __restrict__ Wkv,
                                           const float* __restrict__ kvg,
                                           float* __restrict__ qW,
                                           float* __restrict__ qWg) {
  int h = blockIdx.x >> 4;
  int c0 = (blockIdx.x & 15) * 64;
  int t = threadIdx.x, cl = t & 63, g = t >> 6;
  float a = 0.f;
#pragma unroll 8
  for (int d = g * 32; d < g * 32 + 32; ++d)
    a += qvec[h * DD + d] * Wkv[((size_t)(h * DD + d)) * CC + c0 + cl];
  __shared__ float red[4][64];
  red[g][cl] = a;
  __syncthreads();
  if (t < 64) {
    float v = (red[0][t] + red[1][t] + red[2][t] + red[3][t]) * SCALE_;
    qW[h * CC + c0 + t] = v;
    qWg[h * CC + c0 + t] = v * kvg[c0 + t];
  }
}

// ---- fused single pass over x (v5) ----
__global__ __launch_bounds__(256, 4) void kfused(
    const float* __restrict__ x, const float* __restrict__ qWg,
    const float* __restrict__ qW, const float* __restrict__ kvb,
    float* __restrict__ part_s, float* __restrict__ part_meu) {
  __shared__ __align__(16) float xbuf[2][TPT * CC];  // 2 x 16 KB
  __shared__ __align__(8) float mr_lds[TPT][2];      // {mu, rstd} per row

  const int t = threadIdx.x, lane = t & 63, wid = t >> 6;
  const int chunk = blockIdx.x, b = blockIdx.y;
  const int bc = b * CHUNKS + chunk;
  const int h0 = wid * 2;

  // load this wave's two heads' qWg fragments + kvb fragment
  float4 qw0[4], qw1[4], bt[4];
  {
    const float4* a0 = (const float4*)(qWg + (size_t)h0 * CC);
    const float4* a1 = (const float4*)(qWg + (size_t)(h0 + 1) * CC);
    const float4* b4 = (const float4*)kvb;
#pragma unroll
    for (int k = 0; k < 4; ++k) {
      qw0[k] = a0[lane + 64 * k];
      qw1[k] = a1[lane + 64 * k];
      bt[k] = b4[lane + 64 * k];
    }
  }

  const float* gx = x + ((size_t)b * NN + (size_t)chunk * RPB) * CC;
  stage_tile(gx, xbuf[0], wid, lane);  // tile 0 in flight during prologue math

  // qs = sum(qWg[h,:]); qb = qW[h,:].beta  (wave-uniform)
  float qs0, qs1, qb0, qb1;
  {
    float s0 = 0.f, s1 = 0.f;
#pragma unroll
    for (int k = 0; k < 4; ++k) {
      s0 += qw0[k].x + qw0[k].y + qw0[k].z + qw0[k].w;
      s1 += qw1[k].x + qw1[k].y + qw1[k].z + qw1[k].w;
    }
    qs0 = rsum_u(s0);
    qs1 = rsum_u(s1);
    const float4* w0 = (const float4*)(qW + (size_t)h0 * CC);
    const float4* w1 = (const float4*)(qW + (size_t)(h0 + 1) * CC);
    float t0 = 0.f, t1 = 0.f;
#pragma unroll
    for (int k = 0; k < 4; ++k) {
      t0 += dot4(w0[lane + 64 * k], bt[k]);
      t1 += dot4(w1[lane + 64 * k], bt[k]);
    }
    qb0 = rsum_u(t0);
    qb1 = rsum_u(t1);
  }

  float4 acc0[4], acc1[4];
#pragma unroll
  for (int k = 0; k < 4; ++k) {
    acc0[k] = make_float4(0.f, 0.f, 0.f, 0.f);
    acc1[k] = make_float4(0.f, 0.f, 0.f, 0.f);
  }
  float e0 = 0.f, e1 = 0.f, un0 = 0.f, un1 = 0.f;

  for (int tl = 0; tl < NT; ++tl) {
    bar_vm();  // tile tl landed (issued one full iteration ago); prev buf free

    if (tl + 1 < NT)
      stage_tile(gx + (size_t)(tl + 1) * (TPT * CC), xbuf[(tl + 1) & 1], wid, lane);

    const float4* xb4 = (const float4*)xbuf[tl & 1];

    // ---- phase A: wave 'wid' computes stats for row 'wid' (non-redundant)
    {
      const float4* xr = xb4 + wid * 256;
      float4 x0 = xr[lane], x1 = xr[lane + 64], x2 = xr[lane + 128], x3 = xr[lane + 192];
      float ls = (x0.x + x0.y + x0.z + x0.w) + (x1.x + x1.y + x1.z + x1.w) +
                 (x2.x + x2.y + x2.z + x2.w) + (x3.x + x3.y + x3.z + x3.w);
      float ls2 = dot4(x0, x0) + dot4(x1, x1) + dot4(x2, x2) + dot4(x3, x3);
      ls = dpp_sum63(ls);
      ls2 = dpp_sum63(ls2);
      if (lane == 63) {
        float mu = ls * (1.f / CC);
        float rs = rsqrtf(ls2 * (1.f / CC) - mu * mu + EPS_);
        mr_lds[wid][0] = mu;
        mr_lds[wid][1] = rs;
      }
    }
    bar_lgkm();

    // ---- phase B: branchless; this wave's 2 heads, all 4 rows
#pragma unroll
    for (int r = 0; r < TPT; ++r) {
      float4 x0 = xb4[r * 256 + lane];
      float4 x1 = xb4[r * 256 + lane + 64];
      float4 x2 = xb4[r * 256 + lane + 128];
      float4 x3 = xb4[r * 256 + lane + 192];
      // 4 independent partial chains per head (short dependency depth)
      float a0 = dot4(qw0[0], x0), a1 = dot4(qw0[1], x1);
      float a2 = dot4(qw0[2], x2), a3 = dot4(qw0[3], x3);
      float c0 = dot4(qw1[0], x0), c1 = dot4(qw1[1], x1);
      float c2 = dot4(qw1[2], x2), c3 = dot4(qw1[3], x3);
      float D0 = rsum_u((a0 + a1) + (a2 + a3));
      float D1 = rsum_u((c0 + c1) + (c2 + c3));
      float2 mr = *(const float2*)mr_lds[r];  // broadcast read
      float mu = mr.x, rs = mr.y;
      float l0 = fminf(rs * (D0 - mu * qs0) + qb0, 75.f);  // logits tiny; clamp = inf guard
      float l1 = fminf(rs * (D1 - mu * qs1) + qb1, 75.f);
      float p0 = __expf(l0), p1 = __expf(l1);
      float w0 = p0 * rs, w1 = p1 * rs;
      e0 += p0; e1 += p1;
      un0 += w0 * mu; un1 += w1 * mu;
      fma4(acc0[0], w0, x0); fma4(acc0[1], w0, x1);
      fma4(acc0[2], w0, x2); fma4(acc0[3], w0, x3);
      fma4(acc1[0], w1, x0); fma4(acc1[1], w1, x1);
      fma4(acc1[2], w1, x2); fma4(acc1[3], w1, x3);
    }
  }

  // ---- store partials (m == 0 by construction)
  float4* p0 = (float4*)(part_s + ((size_t)bc * HH + h0) * CC);
  float4* p1 = (float4*)(part_s + ((size_t)bc * HH + h0 + 1) * CC);
#pragma unroll
  for (int k = 0; k < 4; ++k) {
    p0[64 * k + lane] = acc0[k];
    p1[64 * k + lane] = acc1[k];
  }
  if (lane == 0) {
    float* pm = part_meu + ((size_t)bc * HH + h0) * 3;
    pm[0] = 0.f; pm[1] = e0; pm[2] = un0;
    pm[3] = 0.f; pm[4] = e1; pm[5] = un1;
  }
}

// ---- merge partials: s[b,h,c] = gamma*(S-UN)/E + beta ----
__global__ __launch_bounds__(256) void kmerge(
    const float* __restrict__ part_s, const float* __restrict__ part_meu,
    const float* __restrict__ kvg, const float* __restrict__ kvb,
    float* __restrict__ s) {
  int h = blockIdx.x >> 2, q = blockIdx.x & 3, b = blockIdx.y;
  int col = q * 256 + threadIdx.x;
  float M = -3.0e38f;
  for (int ch = 0; ch < CHUNKS; ++ch)
    M = fmaxf(M, part_meu[(((size_t)b * CHUNKS + ch) * HH + h) * 3]);
  float E = 0.f, UN = 0.f, a = 0.f;
  for (int ch = 0; ch < CHUNKS; ++ch) {
    const float* pm = part_meu + (((size_t)b * CHUNKS + ch) * HH + h) * 3;
    float f = __expf(pm[0] - M);
    E += pm[1] * f;
    UN += pm[2] * f;
    a += f * part_s[(((size_t)b * CHUNKS + ch) * HH + h) * CC + col];
  }
  float inv = 1.f / E;
  s[((size_t)b * HH + h) * CC + col] = kvg[col] * (a - UN) * inv + kvb[col];
}

// ---- k5: agg[b,j] = Wkv[C+j,:] . s[b, j/D, :] ----
__global__ __launch_bounds__(256) void k5(const float* __restrict__ Wkv,
                                          const float* __restrict__ s,
                                          float* __restrict__ agg) {
  int lane = threadIdx.x & 63;
  int j = blockIdx.x * 4 + (threadIdx.x >> 6);
  int h = j >> 7;
  const float4* wr = (const float4*)(Wkv + ((size_t)(CC + j)) * CC);
  float4 wv[4];
#pragma unroll
  for (int k = 0; k < 4; ++k) wv[k] = wr[lane + 64 * k];
  for (int b = 0; b < BB; ++b) {
    const float4* s4 = (const float4*)(s + ((size_t)(b * HH + h)) * CC);
    float a = 0.f;
#pragma unroll
    for (int k = 0; k < 4; ++k) a += dot4(wv[k], s4[lane + 64 * k]);
    a = wsum(a);
    if (lane == 0) agg[b * CC + j] = a;
  }
}

// ---- k6: out[b,j] = cf[j] + agg[b,:] . proj_W[j,:] + proj_b[j] ----
__global__ __launch_bounds__(256) void k6(const float* __restrict__ pW,
                                          const float* __restrict__ agg,
                                          const float* __restrict__ cf,
                                          const float* __restrict__ pb,
                                          float* __restrict__ out) {
  int lane = threadIdx.x & 63;
  int j = blockIdx.x * 4 + (threadIdx.x >> 6);
  const float4* wr = (const float4*)(pW + (size_t)j * CC);
  float4 wv[4];
#pragma unroll
  for (int k = 0; k < 4; ++k) wv[k] = wr[lane + 64 * k];
  for (int b = 0; b < BB; ++b) {
    const float4* a4 = (const float4*)(agg + (size_t)b * CC);
    float a = 0.f;
#pragma unroll
    for (int k = 0; k < 4; ++k) a += dot4(wv[k], a4[lane + 64 * k]);
    a = wsum(a);
    if (lane == 0) out[b * CC + j] = cf[j] + a + pb[j];
  }
}

// ws float offsets
constexpr size_t WS_QVEC = 0;        // 1024
constexpr size_t WS_QW   = 1024;     // 8192
constexpr size_t WS_QWG  = 9216;     // 8192
constexpr size_t WS_S    = 17408;    // 131072
constexpr size_t WS_AGG  = 148480;   // 16384
constexpr size_t WS_PMEU = 164864;   // 24576
constexpr size_t WS_PART = 189440;   // 8388608 (33.5 MB)

extern "C" void kernel_launch(void* const* d_in, const int* in_sizes, int n_in,
                              void* d_out, int out_size, void* d_ws, size_t ws_size,
                              hipStream_t stream) {
  const float* cf = (const float*)d_in[0];
  const float* x = (const float*)d_in[1];
  const float* qg = (const float*)d_in[2];
  const float* qb = (const float*)d_in[3];
  const float* Wq = (const float*)d_in[4];
  const float* kvg = (const float*)d_in[5];
  const float* kvb = (const float*)d_in[6];
  const float* Wkv = (const float*)d_in[7];
  const float* pW = (const float*)d_in[8];
  const float* pb = (const float*)d_in[9];
  float* ws = (float*)d_ws;
  float* out = (float*)d_out;

  k0b<<<256, 256, 0, stream>>>(cf, qg, qb, Wq, ws + WS_QVEC);
  k0c<<<128, 256, 0, stream>>>(ws + WS_QVEC, Wkv, kvg, ws + WS_QW, ws + WS_QWG);
  kfused<<<dim3(CHUNKS, BB), 256, 0, stream>>>(x, ws + WS_QWG, ws + WS_QW, kvb,
                                               ws + WS_PART, ws + WS_PMEU);
  kmerge<<<dim3(HH * 4, BB), 256, 0, stream>>>(ws + WS_PART, ws + WS_PMEU, kvg, kvb,
                                               ws + WS_S);
  k5<<<256, 256, 0, stream>>>(Wkv, ws + WS_S, ws + WS_AGG);
  k6<<<256, 256, 0, stream>>>(pW, ws + WS_AGG, cf, pb, out);
}

// Round 6
// 130.848 us; speedup vs baseline: 2.6533x; 2.6533x over previous
//
#include <hip/hip_runtime.h>
#include <math.h>

// GlobalAttention, single-streaming-pass version (v6 = v5 + VGPR fix).
//   logits[b,h,n] = qW[h,:].LN(x[b,n,:])  (q folded through Wkv_k, LN folded via mu/rstd)
//   s[b,h,:]      = sum_n softmax(logits) * rstd_n * x[b,n,:]  (chunk partials, merged)
//   out           = cf + (Wkv_v @ (gamma*(S-UN)/E + beta)) @ proj_W.T + proj_b
// v6: __launch_bounds__(256,2). (256,4) empirically caps VGPR at 64 -> ~40-reg
// in-loop spill -> 1.2 GB scratch traffic (R5: WRITE 560 MB). Demand is ~110 regs.

#define BB 16
#define NN 4096
#define CC 1024
#define HH 8
#define DD 128
#define CHUNKS 64   // chunks per batch
#define RPB 64      // rows per block
#define TPT 4       // rows per tile
#define NT 16       // tiles per block

constexpr float EPS_ = 1e-5f;
constexpr float SCALE_ = 0.03125f; // 1024^-0.5

__device__ __forceinline__ float wsum(float v) {
#pragma unroll
  for (int o = 32; o; o >>= 1) v += __shfl_xor(v, o, 64);
  return v;
}

// DPP wave reduction: sum of all 64 lanes lands in lane 63 (VALU pipe, no LDS).
__device__ __forceinline__ float dpp_sum63(float v) {
  int t;
  t = __builtin_amdgcn_update_dpp(0, __float_as_int(v), 0x111, 0xf, 0xf, true);  v += __int_as_float(t);
  t = __builtin_amdgcn_update_dpp(0, __float_as_int(v), 0x112, 0xf, 0xf, true);  v += __int_as_float(t);
  t = __builtin_amdgcn_update_dpp(0, __float_as_int(v), 0x114, 0xf, 0xf, true);  v += __int_as_float(t);
  t = __builtin_amdgcn_update_dpp(0, __float_as_int(v), 0x118, 0xf, 0xf, true);  v += __int_as_float(t);
  t = __builtin_amdgcn_update_dpp(0, __float_as_int(v), 0x142, 0xa, 0xf, false); v += __int_as_float(t);
  t = __builtin_amdgcn_update_dpp(0, __float_as_int(v), 0x143, 0xc, 0xf, false); v += __int_as_float(t);
  return v;
}

// reduce + broadcast: total of 64 lanes as a wave-uniform value
__device__ __forceinline__ float rsum_u(float v) {
  return __int_as_float(__builtin_amdgcn_readlane(__float_as_int(dpp_sum63(v)), 63));
}

__device__ __forceinline__ float dot4(const float4& a, const float4& b) {
  return a.x * b.x + a.y * b.y + a.z * b.z + a.w * b.w;
}
__device__ __forceinline__ void fma4(float4& a, float s, const float4& v) {
  a.x += s * v.x; a.y += s * v.y; a.z += s * v.z; a.w += s * v.w;
}

// barrier that waits LDS ops only (keeps global_load_lds prefetch in flight)
__device__ __forceinline__ void bar_lgkm() {
  asm volatile("s_waitcnt lgkmcnt(0)" ::: "memory");
  __builtin_amdgcn_sched_barrier(0);
  __builtin_amdgcn_s_barrier();
  __builtin_amdgcn_sched_barrier(0);
}
// barrier that waits all outstanding global_load_lds (tile ready)
__device__ __forceinline__ void bar_vm() {
  asm volatile("s_waitcnt vmcnt(0)" ::: "memory");
  __builtin_amdgcn_sched_barrier(0);
  __builtin_amdgcn_s_barrier();
  __builtin_amdgcn_sched_barrier(0);
}

// stage one 4-row tile (16 KB) into LDS: 4 x global_load_lds dwordx4 per thread.
__device__ __forceinline__ void stage_tile(const float* gsrc, float* lbase,
                                           int wid, int lane) {
#pragma unroll
  for (int k = 0; k < 4; ++k) {
    const char* g = (const char*)gsrc + k * 4096 + wid * 1024 + lane * 16;
    char* l = (char*)lbase + k * 4096 + wid * 1024;
    __builtin_amdgcn_global_load_lds(
        (const __attribute__((address_space(1))) void*)g,
        (__attribute__((address_space(3))) void*)l, 16, 0, 0);
  }
}

// ---- k0b: LN(class_feature) in-block, then qvec[j] = ln_cf . Wq[j,:] ----
__global__ __launch_bounds__(256) void k0b(const float* __restrict__ cf,
                                           const float* __restrict__ g,
                                           const float* __restrict__ be,
                                           const float* __restrict__ Wq,
                                           float* __restrict__ qvec) {
  __shared__ __align__(16) float lnbuf[CC];
  __shared__ float red[8];
  int t = threadIdx.x, lane = t & 63, wid = t >> 6;
  float x[4];
  float s = 0.f, s2 = 0.f;
#pragma unroll
  for (int j = 0; j < 4; ++j) {
    x[j] = cf[t * 4 + j];
    s += x[j];
    s2 += x[j] * x[j];
  }
  s = wsum(s);
  s2 = wsum(s2);
  if (lane == 0) { red[wid] = s; red[4 + wid] = s2; }
  __syncthreads();
  float S = red[0] + red[1] + red[2] + red[3];
  float S2 = red[4] + red[5] + red[6] + red[7];
  float mu = S * (1.f / CC);
  float rstd = rsqrtf(S2 * (1.f / CC) - mu * mu + EPS_);
#pragma unroll
  for (int j = 0; j < 4; ++j)
    lnbuf[t * 4 + j] = (x[j] - mu) * rstd * g[t * 4 + j] + be[t * 4 + j];
  __syncthreads();
  int j = blockIdx.x * 4 + wid;
  const float4* wr = (const float4*)(Wq + (size_t)j * CC);
  const float4* l4 = (const float4*)lnbuf;
  float a = 0.f;
#pragma unroll
  for (int k = 0; k < 4; ++k) a += dot4(wr[lane + 64 * k], l4[lane + 64 * k]);
  a = wsum(a);
  if (lane == 0) qvec[j] = a;
}

// ---- k0c: qW[h,c] = scale*sum_d qvec[h*D+d]*Wkv[h*D+d,c]; qWg = qW*gamma ----
__global__ __launch_bounds__(256) void k0c(const float* __restrict__ qvec,
                                           const float* __restrict__ Wkv,
                                           const float* __restrict__ kvg,
                                           float* __restrict__ qW,
                                           float* __restrict__ qWg) {
  int h = blockIdx.x >> 4;
  int c0 = (blockIdx.x & 15) * 64;
  int t = threadIdx.x, cl = t & 63, g = t >> 6;
  float a = 0.f;
#pragma unroll 8
  for (int d = g * 32; d < g * 32 + 32; ++d)
    a += qvec[h * DD + d] * Wkv[((size_t)(h * DD + d)) * CC + c0 + cl];
  __shared__ float red[4][64];
  red[g][cl] = a;
  __syncthreads();
  if (t < 64) {
    float v = (red[0][t] + red[1][t] + red[2][t] + red[3][t]) * SCALE_;
    qW[h * CC + c0 + t] = v;
    qWg[h * CC + c0 + t] = v * kvg[c0 + t];
  }
}

// ---- fused single pass over x (v6) ----
__global__ __launch_bounds__(256, 2) void kfused(
    const float* __restrict__ x, const float* __restrict__ qWg,
    const float* __restrict__ qW, const float* __restrict__ kvb,
    float* __restrict__ part_s, float* __restrict__ part_meu) {
  __shared__ __align__(16) float xbuf[2][TPT * CC];  // 2 x 16 KB
  __shared__ __align__(8) float mr_lds[TPT][2];      // {mu, rstd} per row

  const int t = threadIdx.x, lane = t & 63, wid = t >> 6;
  const int chunk = blockIdx.x, b = blockIdx.y;
  const int bc = b * CHUNKS + chunk;
  const int h0 = wid * 2;

  const float* gx = x + ((size_t)b * NN + (size_t)chunk * RPB) * CC;
  stage_tile(gx, xbuf[0], wid, lane);  // tile 0 in flight during prologue math

  // load this wave's two heads' qWg fragments (live across the whole loop)
  float4 qw0[4], qw1[4];
  {
    const float4* a0 = (const float4*)(qWg + (size_t)h0 * CC);
    const float4* a1 = (const float4*)(qWg + (size_t)(h0 + 1) * CC);
#pragma unroll
    for (int k = 0; k < 4; ++k) {
      qw0[k] = a0[lane + 64 * k];
      qw1[k] = a1[lane + 64 * k];
    }
  }
  // qs = sum(qWg[h,:]); qb = qW[h,:].beta  (wave-uniform; kvb/qW not kept live)
  float qs0, qs1, qb0, qb1;
  {
    float s0 = 0.f, s1 = 0.f, t0 = 0.f, t1 = 0.f;
    const float4* w0 = (const float4*)(qW + (size_t)h0 * CC);
    const float4* w1 = (const float4*)(qW + (size_t)(h0 + 1) * CC);
    const float4* b4 = (const float4*)kvb;
#pragma unroll
    for (int k = 0; k < 4; ++k) {
      s0 += qw0[k].x + qw0[k].y + qw0[k].z + qw0[k].w;
      s1 += qw1[k].x + qw1[k].y + qw1[k].z + qw1[k].w;
      float4 bt = b4[lane + 64 * k];
      t0 += dot4(w0[lane + 64 * k], bt);
      t1 += dot4(w1[lane + 64 * k], bt);
    }
    qs0 = rsum_u(s0);
    qs1 = rsum_u(s1);
    qb0 = rsum_u(t0);
    qb1 = rsum_u(t1);
  }

  float4 acc0[4], acc1[4];
#pragma unroll
  for (int k = 0; k < 4; ++k) {
    acc0[k] = make_float4(0.f, 0.f, 0.f, 0.f);
    acc1[k] = make_float4(0.f, 0.f, 0.f, 0.f);
  }
  float e0 = 0.f, e1 = 0.f, un0 = 0.f, un1 = 0.f;

  for (int tl = 0; tl < NT; ++tl) {
    bar_vm();  // tile tl landed (issued one full iteration ago); prev buf free

    if (tl + 1 < NT)
      stage_tile(gx + (size_t)(tl + 1) * (TPT * CC), xbuf[(tl + 1) & 1], wid, lane);

    const float4* xb4 = (const float4*)xbuf[tl & 1];

    // ---- phase A: wave 'wid' computes stats for row 'wid' (non-redundant)
    {
      const float4* xr = xb4 + wid * 256;
      float4 x0 = xr[lane], x1 = xr[lane + 64], x2 = xr[lane + 128], x3 = xr[lane + 192];
      float ls = (x0.x + x0.y + x0.z + x0.w) + (x1.x + x1.y + x1.z + x1.w) +
                 (x2.x + x2.y + x2.z + x2.w) + (x3.x + x3.y + x3.z + x3.w);
      float ls2 = dot4(x0, x0) + dot4(x1, x1) + dot4(x2, x2) + dot4(x3, x3);
      ls = dpp_sum63(ls);
      ls2 = dpp_sum63(ls2);
      if (lane == 63) {
        float mu = ls * (1.f / CC);
        float rs = rsqrtf(ls2 * (1.f / CC) - mu * mu + EPS_);
        mr_lds[wid][0] = mu;
        mr_lds[wid][1] = rs;
      }
    }
    bar_lgkm();

    // ---- phase B: branchless; this wave's 2 heads, all 4 rows
#pragma unroll
    for (int r = 0; r < TPT; ++r) {
      float4 x0 = xb4[r * 256 + lane];
      float4 x1 = xb4[r * 256 + lane + 64];
      float4 x2 = xb4[r * 256 + lane + 128];
      float4 x3 = xb4[r * 256 + lane + 192];
      // 4 independent partial chains per head (short dependency depth)
      float a0 = dot4(qw0[0], x0), a1 = dot4(qw0[1], x1);
      float a2 = dot4(qw0[2], x2), a3 = dot4(qw0[3], x3);
      float c0 = dot4(qw1[0], x0), c1 = dot4(qw1[1], x1);
      float c2 = dot4(qw1[2], x2), c3 = dot4(qw1[3], x3);
      float D0 = rsum_u((a0 + a1) + (a2 + a3));
      float D1 = rsum_u((c0 + c1) + (c2 + c3));
      float2 mr = *(const float2*)mr_lds[r];  // broadcast read
      float mu = mr.x, rs = mr.y;
      float l0 = fminf(rs * (D0 - mu * qs0) + qb0, 75.f);  // logits tiny; clamp = inf guard
      float l1 = fminf(rs * (D1 - mu * qs1) + qb1, 75.f);
      float p0 = __expf(l0), p1 = __expf(l1);
      float w0 = p0 * rs, w1 = p1 * rs;
      e0 += p0; e1 += p1;
      un0 += w0 * mu; un1 += w1 * mu;
      fma4(acc0[0], w0, x0); fma4(acc0[1], w0, x1);
      fma4(acc0[2], w0, x2); fma4(acc0[3], w0, x3);
      fma4(acc1[0], w1, x0); fma4(acc1[1], w1, x1);
      fma4(acc1[2], w1, x2); fma4(acc1[3], w1, x3);
    }
  }

  // ---- store partials (m == 0 by construction)
  float4* p0 = (float4*)(part_s + ((size_t)bc * HH + h0) * CC);
  float4* p1 = (float4*)(part_s + ((size_t)bc * HH + h0 + 1) * CC);
#pragma unroll
  for (int k = 0; k < 4; ++k) {
    p0[64 * k + lane] = acc0[k];
    p1[64 * k + lane] = acc1[k];
  }
  if (lane == 0) {
    float* pm = part_meu + ((size_t)bc * HH + h0) * 3;
    pm[0] = 0.f; pm[1] = e0; pm[2] = un0;
    pm[3] = 0.f; pm[4] = e1; pm[5] = un1;
  }
}

// ---- merge partials: s[b,h,c] = gamma*(S-UN)/E + beta ----
__global__ __launch_bounds__(256) void kmerge(
    const float* __restrict__ part_s, const float* __restrict__ part_meu,
    const float* __restrict__ kvg, const float* __restrict__ kvb,
    float* __restrict__ s) {
  int h = blockIdx.x >> 2, q = blockIdx.x & 3, b = blockIdx.y;
  int col = q * 256 + threadIdx.x;
  float E = 0.f, UN = 0.f, a = 0.f;
  for (int ch = 0; ch < CHUNKS; ++ch) {
    const float* pm = part_meu + (((size_t)b * CHUNKS + ch) * HH + h) * 3;
    E += pm[1];
    UN += pm[2];
    a += part_s[(((size_t)b * CHUNKS + ch) * HH + h) * CC + col];
  }
  float inv = 1.f / E;
  s[((size_t)b * HH + h) * CC + col] = kvg[col] * (a - UN) * inv + kvb[col];
}

// ---- k5: agg[b,j] = Wkv[C+j,:] . s[b, j/D, :] ----
__global__ __launch_bounds__(256) void k5(const float* __restrict__ Wkv,
                                          const float* __restrict__ s,
                                          float* __restrict__ agg) {
  int lane = threadIdx.x & 63;
  int j = blockIdx.x * 4 + (threadIdx.x >> 6);
  int h = j >> 7;
  const float4* wr = (const float4*)(Wkv + ((size_t)(CC + j)) * CC);
  float4 wv[4];
#pragma unroll
  for (int k = 0; k < 4; ++k) wv[k] = wr[lane + 64 * k];
  for (int b = 0; b < BB; ++b) {
    const float4* s4 = (const float4*)(s + ((size_t)(b * HH + h)) * CC);
    float a = 0.f;
#pragma unroll
    for (int k = 0; k < 4; ++k) a += dot4(wv[k], s4[lane + 64 * k]);
    a = wsum(a);
    if (lane == 0) agg[b * CC + j] = a;
  }
}

// ---- k6: out[b,j] = cf[j] + agg[b,:] . proj_W[j,:] + proj_b[j] ----
__global__ __launch_bounds__(256) void k6(const float* __restrict__ pW,
                                          const float* __restrict__ agg,
                                          const float* __restrict__ cf,
                                          const float* __restrict__ pb,
                                          float* __restrict__ out) {
  int lane = threadIdx.x & 63;
  int j = blockIdx.x * 4 + (threadIdx.x >> 6);
  const float4* wr = (const float4*)(pW + (size_t)j * CC);
  float4 wv[4];
#pragma unroll
  for (int k = 0; k < 4; ++k) wv[k] = wr[lane + 64 * k];
  for (int b = 0; b < BB; ++b) {
    const float4* a4 = (const float4*)(agg + (size_t)b * CC);
    float a = 0.f;
#pragma unroll
    for (int k = 0; k < 4; ++k) a += dot4(wv[k], a4[lane + 64 * k]);
    a = wsum(a);
    if (lane == 0) out[b * CC + j] = cf[j] + a + pb[j];
  }
}

// ws float offsets
constexpr size_t WS_QVEC = 0;        // 1024
constexpr size_t WS_QW   = 1024;     // 8192
constexpr size_t WS_QWG  = 9216;     // 8192
constexpr size_t WS_S    = 17408;    // 131072
constexpr size_t WS_AGG  = 148480;   // 16384
constexpr size_t WS_PMEU = 164864;   // 24576
constexpr size_t WS_PART = 189440;   // 8388608 (33.5 MB)

extern "C" void kernel_launch(void* const* d_in, const int* in_sizes, int n_in,
                              void* d_out, int out_size, void* d_ws, size_t ws_size,
                              hipStream_t stream) {
  const float* cf = (const float*)d_in[0];
  const float* x = (const float*)d_in[1];
  const float* qg = (const float*)d_in[2];
  const float* qb = (const float*)d_in[3];
  const float* Wq = (const float*)d_in[4];
  const float* kvg = (const float*)d_in[5];
  const float* kvb = (const float*)d_in[6];
  const float* Wkv = (const float*)d_in[7];
  const float* pW = (const float*)d_in[8];
  const float* pb = (const float*)d_in[9];
  float* ws = (float*)d_ws;
  float* out = (float*)d_out;

  k0b<<<256, 256, 0, stream>>>(cf, qg, qb, Wq, ws + WS_QVEC);
  k0c<<<128, 256, 0, stream>>>(ws + WS_QVEC, Wkv, kvg, ws + WS_QW, ws + WS_QWG);
  kfused<<<dim3(CHUNKS, BB), 256, 0, stream>>>(x, ws + WS_QWG, ws + WS_QW, kvb,
                                               ws + WS_PART, ws + WS_PMEU);
  kmerge<<<dim3(HH * 4, BB), 256, 0, stream>>>(ws + WS_PART, ws + WS_PMEU, kvg, kvb,
                                               ws + WS_S);
  k5<<<256, 256, 0, stream>>>(Wkv, ws + WS_S, ws + WS_AGG);
  k6<<<256, 256, 0, stream>>>(pW, ws + WS_AGG, cf, pb, out);
}

// Round 7
// 114.116 us; speedup vs baseline: 3.0423x; 1.1466x over previous
//
#include <hip/hip_runtime.h>
#include <math.h>

// GlobalAttention, single-streaming-pass version (v7).
//   logits[b,h,n] = qW[h,:].LN(x[b,n,:])  (q folded through Wkv_k, LN folded via mu/rstd)
//   s[b,h,:]      = sum_n softmax(logits) * rstd_n * x[b,n,:]  (chunk partials, merged)
//   out           = cf + (Wkv_v @ (gamma*(S-UN)/E + beta)) @ proj_b etc.
// v7: reg-staging (global->reg->LDS) with stats computed from the staging
// registers (row == wid, wave-local reduce) -> ONE lgkm-only barrier per tile,
// no separate phase A pass. Double-buffered xbuf and mr_lds; max skew 1 tile.

#define BB 16
#define NN 4096
#define CC 1024
#define HH 8
#define DD 128
#define CHUNKS 64   // chunks per batch
#define RPB 64      // rows per block
#define TPT 4       // rows per tile
#define NT 16       // tiles per block

constexpr float EPS_ = 1e-5f;
constexpr float SCALE_ = 0.03125f; // 1024^-0.5

__device__ __forceinline__ float wsum(float v) {
#pragma unroll
  for (int o = 32; o; o >>= 1) v += __shfl_xor(v, o, 64);
  return v;
}

// DPP wave reduction: sum of all 64 lanes lands in lane 63 (VALU pipe, no LDS).
__device__ __forceinline__ float dpp_sum63(float v) {
  int t;
  t = __builtin_amdgcn_update_dpp(0, __float_as_int(v), 0x111, 0xf, 0xf, true);  v += __int_as_float(t);
  t = __builtin_amdgcn_update_dpp(0, __float_as_int(v), 0x112, 0xf, 0xf, true);  v += __int_as_float(t);
  t = __builtin_amdgcn_update_dpp(0, __float_as_int(v), 0x114, 0xf, 0xf, true);  v += __int_as_float(t);
  t = __builtin_amdgcn_update_dpp(0, __float_as_int(v), 0x118, 0xf, 0xf, true);  v += __int_as_float(t);
  t = __builtin_amdgcn_update_dpp(0, __float_as_int(v), 0x142, 0xa, 0xf, false); v += __int_as_float(t);
  t = __builtin_amdgcn_update_dpp(0, __float_as_int(v), 0x143, 0xc, 0xf, false); v += __int_as_float(t);
  return v;
}

// reduce + broadcast: total of 64 lanes as a wave-uniform value
__device__ __forceinline__ float rsum_u(float v) {
  return __int_as_float(__builtin_amdgcn_readlane(__float_as_int(dpp_sum63(v)), 63));
}

__device__ __forceinline__ float dot4(const float4& a, const float4& b) {
  return a.x * b.x + a.y * b.y + a.z * b.z + a.w * b.w;
}
__device__ __forceinline__ void fma4(float4& a, float s, const float4& v) {
  a.x += s * v.x; a.y += s * v.y; a.z += s * v.z; a.w += s * v.w;
}

// barrier that waits LDS ops only (keeps global prefetch loads in flight)
__device__ __forceinline__ void bar_lgkm() {
  asm volatile("s_waitcnt lgkmcnt(0)" ::: "memory");
  __builtin_amdgcn_sched_barrier(0);
  __builtin_amdgcn_s_barrier();
  __builtin_amdgcn_sched_barrier(0);
}

// ---- k0b: LN(class_feature) in-block, then qvec[j] = ln_cf . Wq[j,:] ----
__global__ __launch_bounds__(256) void k0b(const float* __restrict__ cf,
                                           const float* __restrict__ g,
                                           const float* __restrict__ be,
                                           const float* __restrict__ Wq,
                                           float* __restrict__ qvec) {
  __shared__ __align__(16) float lnbuf[CC];
  __shared__ float red[8];
  int t = threadIdx.x, lane = t & 63, wid = t >> 6;
  float x[4];
  float s = 0.f, s2 = 0.f;
#pragma unroll
  for (int j = 0; j < 4; ++j) {
    x[j] = cf[t * 4 + j];
    s += x[j];
    s2 += x[j] * x[j];
  }
  s = wsum(s);
  s2 = wsum(s2);
  if (lane == 0) { red[wid] = s; red[4 + wid] = s2; }
  __syncthreads();
  float S = red[0] + red[1] + red[2] + red[3];
  float S2 = red[4] + red[5] + red[6] + red[7];
  float mu = S * (1.f / CC);
  float rstd = rsqrtf(S2 * (1.f / CC) - mu * mu + EPS_);
#pragma unroll
  for (int j = 0; j < 4; ++j)
    lnbuf[t * 4 + j] = (x[j] - mu) * rstd * g[t * 4 + j] + be[t * 4 + j];
  __syncthreads();
  int j = blockIdx.x * 4 + wid;
  const float4* wr = (const float4*)(Wq + (size_t)j * CC);
  const float4* l4 = (const float4*)lnbuf;
  float a = 0.f;
#pragma unroll
  for (int k = 0; k < 4; ++k) a += dot4(wr[lane + 64 * k], l4[lane + 64 * k]);
  a = wsum(a);
  if (lane == 0) qvec[j] = a;
}

// ---- k0c: qW[h,c] = scale*sum_d qvec[h*D+d]*Wkv[h*D+d,c]; qWg = qW*gamma ----
__global__ __launch_bounds__(256) void k0c(const float* __restrict__ qvec,
                                           const float* __restrict__ Wkv,
                                           const float* __restrict__ kvg,
                                           float* __restrict__ qW,
                                           float* __restrict__ qWg) {
  int h = blockIdx.x >> 4;
  int c0 = (blockIdx.x & 15) * 64;
  int t = threadIdx.x, cl = t & 63, g = t >> 6;
  float a = 0.f;
#pragma unroll 8
  for (int d = g * 32; d < g * 32 + 32; ++d)
    a += qvec[h * DD + d] * Wkv[((size_t)(h * DD + d)) * CC + c0 + cl];
  __shared__ float red[4][64];
  red[g][cl] = a;
  __syncthreads();
  if (t < 64) {
    float v = (red[0][t] + red[1][t] + red[2][t] + red[3][t]) * SCALE_;
    qW[h * CC + c0 + t] = v;
    qWg[h * CC + c0 + t] = v * kvg[c0 + t];
  }
}

// ---- fused single pass over x (v7) ----
__global__ __launch_bounds__(256, 2) void kfused(
    const float* __restrict__ x, const float* __restrict__ qWg,
    const float* __restrict__ qW, const float* __restrict__ kvb,
    float* __restrict__ part_s, float* __restrict__ part_meu) {
  __shared__ __align__(16) float xbuf[2][TPT * CC];  // 2 x 16 KB
  __shared__ __align__(8) float mr_lds[2][TPT][2];   // {mu, rstd}, double-buffered

  const int t = threadIdx.x, lane = t & 63, wid = t >> 6;
  const int chunk = blockIdx.x, b = blockIdx.y;
  const int bc = b * CHUNKS + chunk;
  const int h0 = wid * 2;

  const float* gx = x + ((size_t)b * NN + (size_t)chunk * RPB) * CC;
  // thread t's slice of a tile: row 'wid', float4 cols (lane + 64k), k=0..3
  const int sl = wid * 256 + lane;

  // prefetch tile 0 into regs (in flight during prologue math)
  float4 pf[4];
  {
    const float4* g0 = (const float4*)gx;
#pragma unroll
    for (int k = 0; k < 4; ++k) pf[k] = g0[sl + 64 * k];
  }

  // this wave's two heads' qWg fragments (live across the whole loop)
  float4 qw0[4], qw1[4];
  {
    const float4* a0 = (const float4*)(qWg + (size_t)h0 * CC);
    const float4* a1 = (const float4*)(qWg + (size_t)(h0 + 1) * CC);
#pragma unroll
    for (int k = 0; k < 4; ++k) {
      qw0[k] = a0[lane + 64 * k];
      qw1[k] = a1[lane + 64 * k];
    }
  }
  // qs = sum(qWg[h,:]); qb = qW[h,:].beta  (wave-uniform)
  float qs0, qs1, qb0, qb1;
  {
    float s0 = 0.f, s1 = 0.f, t0 = 0.f, t1 = 0.f;
    const float4* w0 = (const float4*)(qW + (size_t)h0 * CC);
    const float4* w1 = (const float4*)(qW + (size_t)(h0 + 1) * CC);
    const float4* b4 = (const float4*)kvb;
#pragma unroll
    for (int k = 0; k < 4; ++k) {
      s0 += qw0[k].x + qw0[k].y + qw0[k].z + qw0[k].w;
      s1 += qw1[k].x + qw1[k].y + qw1[k].z + qw1[k].w;
      float4 bt = b4[lane + 64 * k];
      t0 += dot4(w0[lane + 64 * k], bt);
      t1 += dot4(w1[lane + 64 * k], bt);
    }
    qs0 = rsum_u(s0);
    qs1 = rsum_u(s1);
    qb0 = rsum_u(t0);
    qb1 = rsum_u(t1);
  }

  float4 acc0[4], acc1[4];
#pragma unroll
  for (int k = 0; k < 4; ++k) {
    acc0[k] = make_float4(0.f, 0.f, 0.f, 0.f);
    acc1[k] = make_float4(0.f, 0.f, 0.f, 0.f);
  }
  float e0 = 0.f, e1 = 0.f, un0 = 0.f, un1 = 0.f;

  for (int tl = 0; tl < NT; ++tl) {
    const int cur = tl & 1;
    // ---- stats for row 'wid' directly from the staging registers
    float ls = 0.f, ls2 = 0.f;
#pragma unroll
    for (int k = 0; k < 4; ++k) {
      ls += pf[k].x + pf[k].y + pf[k].z + pf[k].w;
      ls2 += dot4(pf[k], pf[k]);
    }
    // ---- write tile to LDS (same layout phase B reads)
    {
      float4* dst = (float4*)xbuf[cur];
#pragma unroll
      for (int k = 0; k < 4; ++k) dst[sl + 64 * k] = pf[k];
    }
    // ---- reduce stats; lane 63 publishes {mu, rstd}
    ls = dpp_sum63(ls);
    ls2 = dpp_sum63(ls2);
    if (lane == 63) {
      float mu = ls * (1.f / CC);
      float rs = rsqrtf(ls2 * (1.f / CC) - mu * mu + EPS_);
      mr_lds[cur][wid][0] = mu;
      mr_lds[cur][wid][1] = rs;
    }
    // ---- issue next tile's prefetch (regs now free; lands during phase B)
    if (tl + 1 < NT) {
      const float4* gn = (const float4*)(gx + (size_t)(tl + 1) * (TPT * CC));
#pragma unroll
      for (int k = 0; k < 4; ++k) pf[k] = gn[sl + 64 * k];
    }
    // ---- one barrier: ds_writes + mr_lds visible; prefetch stays in flight
    bar_lgkm();

    // ---- phase B: branchless; this wave's 2 heads, all 4 rows
    const float4* xb4 = (const float4*)xbuf[cur];
#pragma unroll
    for (int r = 0; r < TPT; ++r) {
      float4 x0 = xb4[r * 256 + lane];
      float4 x1 = xb4[r * 256 + lane + 64];
      float4 x2 = xb4[r * 256 + lane + 128];
      float4 x3 = xb4[r * 256 + lane + 192];
      float a0 = dot4(qw0[0], x0), a1 = dot4(qw0[1], x1);
      float a2 = dot4(qw0[2], x2), a3 = dot4(qw0[3], x3);
      float c0 = dot4(qw1[0], x0), c1 = dot4(qw1[1], x1);
      float c2 = dot4(qw1[2], x2), c3 = dot4(qw1[3], x3);
      float D0 = rsum_u((a0 + a1) + (a2 + a3));
      float D1 = rsum_u((c0 + c1) + (c2 + c3));
      float2 mr = *(const float2*)mr_lds[cur][r];  // broadcast read
      float mu = mr.x, rs = mr.y;
      float l0 = fminf(rs * (D0 - mu * qs0) + qb0, 75.f);  // logits tiny; clamp = inf guard
      float l1 = fminf(rs * (D1 - mu * qs1) + qb1, 75.f);
      float p0 = __expf(l0), p1 = __expf(l1);
      float w0 = p0 * rs, w1 = p1 * rs;
      e0 += p0; e1 += p1;
      un0 += w0 * mu; un1 += w1 * mu;
      fma4(acc0[0], w0, x0); fma4(acc0[1], w0, x1);
      fma4(acc0[2], w0, x2); fma4(acc0[3], w0, x3);
      fma4(acc1[0], w1, x0); fma4(acc1[1], w1, x1);
      fma4(acc1[2], w1, x2); fma4(acc1[3], w1, x3);
    }
  }

  // ---- store partials (m == 0 by construction; logits bounded ~|2|)
  float4* p0 = (float4*)(part_s + ((size_t)bc * HH + h0) * CC);
  float4* p1 = (float4*)(part_s + ((size_t)bc * HH + h0 + 1) * CC);
#pragma unroll
  for (int k = 0; k < 4; ++k) {
    p0[64 * k + lane] = acc0[k];
    p1[64 * k + lane] = acc1[k];
  }
  if (lane == 0) {
    float* pm = part_meu + ((size_t)bc * HH + h0) * 3;
    pm[0] = 0.f; pm[1] = e0; pm[2] = un0;
    pm[3] = 0.f; pm[4] = e1; pm[5] = un1;
  }
}

// ---- merge partials: s[b,h,c] = gamma*(S-UN)/E + beta ----
__global__ __launch_bounds__(256) void kmerge(
    const float* __restrict__ part_s, const float* __restrict__ part_meu,
    const float* __restrict__ kvg, const float* __restrict__ kvb,
    float* __restrict__ s) {
  int h = blockIdx.x >> 2, q = blockIdx.x & 3, b = blockIdx.y;
  int col = q * 256 + threadIdx.x;
  float E = 0.f, UN = 0.f, a = 0.f;
  for (int ch = 0; ch < CHUNKS; ++ch) {
    const float* pm = part_meu + (((size_t)b * CHUNKS + ch) * HH + h) * 3;
    E += pm[1];
    UN += pm[2];
    a += part_s[(((size_t)b * CHUNKS + ch) * HH + h) * CC + col];
  }
  float inv = 1.f / E;
  s[((size_t)b * HH + h) * CC + col] = kvg[col] * (a - UN) * inv + kvb[col];
}

// ---- k5: agg[b,j] = Wkv[C+j,:] . s[b, j/D, :] ----
__global__ __launch_bounds__(256) void k5(const float* __restrict__ Wkv,
                                          const float* __restrict__ s,
                                          float* __restrict__ agg) {
  int lane = threadIdx.x & 63;
  int j = blockIdx.x * 4 + (threadIdx.x >> 6);
  int h = j >> 7;
  const float4* wr = (const float4*)(Wkv + ((size_t)(CC + j)) * CC);
  float4 wv[4];
#pragma unroll
  for (int k = 0; k < 4; ++k) wv[k] = wr[lane + 64 * k];
  for (int b = 0; b < BB; ++b) {
    const float4* s4 = (const float4*)(s + ((size_t)(b * HH + h)) * CC);
    float a = 0.f;
#pragma unroll
    for (int k = 0; k < 4; ++k) a += dot4(wv[k], s4[lane + 64 * k]);
    a = wsum(a);
    if (lane == 0) agg[b * CC + j] = a;
  }
}

// ---- k6: out[b,j] = cf[j] + agg[b,:] . proj_W[j,:] + proj_b[j] ----
__global__ __launch_bounds__(256) void k6(const float* __restrict__ pW,
                                          const float* __restrict__ agg,
                                          const float* __restrict__ cf,
                                          const float* __restrict__ pb,
                                          float* __restrict__ out) {
  int lane = threadIdx.x & 63;
  int j = blockIdx.x * 4 + (threadIdx.x >> 6);
  const float4* wr = (const float4*)(pW + (size_t)j * CC);
  float4 wv[4];
#pragma unroll
  for (int k = 0; k < 4; ++k) wv[k] = wr[lane + 64 * k];
  for (int b = 0; b < BB; ++b) {
    const float4* a4 = (const float4*)(agg + (size_t)b * CC);
    float a = 0.f;
#pragma unroll
    for (int k = 0; k < 4; ++k) a += dot4(wv[k], a4[lane + 64 * k]);
    a = wsum(a);
    if (lane == 0) out[b * CC + j] = cf[j] + a + pb[j];
  }
}

// ws float offsets
constexpr size_t WS_QVEC = 0;        // 1024
constexpr size_t WS_QW   = 1024;     // 8192
constexpr size_t WS_QWG  = 9216;     // 8192
constexpr size_t WS_S    = 17408;    // 131072
constexpr size_t WS_AGG  = 148480;   // 16384
constexpr size_t WS_PMEU = 164864;   // 24576
constexpr size_t WS_PART = 189440;   // 8388608 (33.5 MB)

extern "C" void kernel_launch(void* const* d_in, const int* in_sizes, int n_in,
                              void* d_out, int out_size, void* d_ws, size_t ws_size,
                              hipStream_t stream) {
  const float* cf = (const float*)d_in[0];
  const float* x = (const float*)d_in[1];
  const float* qg = (const float*)d_in[2];
  const float* qb = (const float*)d_in[3];
  const float* Wq = (const float*)d_in[4];
  const float* kvg = (const float*)d_in[5];
  const float* kvb = (const float*)d_in[6];
  const float* Wkv = (const float*)d_in[7];
  const float* pW = (const float*)d_in[8];
  const float* pb = (const float*)d_in[9];
  float* ws = (float*)d_ws;
  float* out = (float*)d_out;

  k0b<<<256, 256, 0, stream>>>(cf, qg, qb, Wq, ws + WS_QVEC);
  k0c<<<128, 256, 0, stream>>>(ws + WS_QVEC, Wkv, kvg, ws + WS_QW, ws + WS_QWG);
  kfused<<<dim3(CHUNKS, BB), 256, 0, stream>>>(x, ws + WS_QWG, ws + WS_QW, kvb,
                                               ws + WS_PART, ws + WS_PMEU);
  kmerge<<<dim3(HH * 4, BB), 256, 0, stream>>>(ws + WS_PART, ws + WS_PMEU, kvg, kvb,
                                               ws + WS_S);
  k5<<<256, 256, 0, stream>>>(Wkv, ws + WS_S, ws + WS_AGG);
  k6<<<256, 256, 0, stream>>>(pW, ws + WS_AGG, cf, pb, out);
}